// Round 3
// baseline (2000.581 us; speedup 1.0000x reference)
//
#include <hip/hip_runtime.h>

typedef _Float16 half8 __attribute__((ext_vector_type(8)));
typedef _Float16 f16x2 __attribute__((ext_vector_type(2)));
typedef float floatx4 __attribute__((ext_vector_type(4)));

#define NB 256    // batch
#define NT 512    // time
#define NI 64     // input
#define NH 256    // hidden
#define NSEQ 16   // sequences per block
#define NBLK (NB / NSEQ)   // 16 blocks
#define THR 256            // 4 waves, 1 wave/SIMD -> 512 VGPR unified budget
#define HS 344             // H row stride in f16

// B-fragment pack (VALIDATED R9/R10): 480 frags x 64 lanes x 8 f16.
// Cols: [0,256)=r, [256,512)=z, [512,768)=h_n, [768,1024)=i_n. K: [0,256)=h, [256,320)=x.
// frag f: r: tt*10+kb; z: 160+tt*10+kb; h_n: 320+tt*8+kb (kb<8); i_n: 448+tt*2+(kb-8).
// wb[f*512 + lane*8 + i] = W[k = kb*32 + (lane>>4)*8 + i][n = tt*16 + (lane&15)]
#define WB_N (480 * 512)

__global__ __launch_bounds__(256) void gru_prep_kernel(
    const float* __restrict__ w_ih, const float* __restrict__ w_hh,
    _Float16* __restrict__ wb)
{
  int n = blockIdx.x * 256 + threadIdx.x;
  if (n >= WB_N) return;
  int i = n & 7, l = (n >> 3) & 63, f = n >> 9;
  int q = l >> 4, col = l & 15;
  int tt, kb, gate;
  if (f < 160)      { tt = f / 10;               kb = f % 10;        gate = 0; }
  else if (f < 320) { int f2 = f - 160; tt = f2 / 10; kb = f2 % 10;  gate = 1; }
  else if (f < 448) { int f3 = f - 320; tt = f3 / 8;  kb = f3 % 8;   gate = 2; }
  else              { int f4 = f - 448; tt = f4 / 2;  kb = 8 + (f4 & 1); gate = 3; }
  int j = (tt & 15) * 16 + col;
  int k = kb * 32 + q * 8 + i;
  float v;
  if (gate == 0)      v = (k < 256) ? w_hh[(0   + j) * 256 + k] : w_ih[(0   + j) * 64 + (k - 256)];
  else if (gate == 1) v = (k < 256) ? w_hh[(256 + j) * 256 + k] : w_ih[(256 + j) * 64 + (k - 256)];
  else if (gate == 2) v = w_hh[(512 + j) * 256 + k];
  else                v = w_ih[(512 + j) * 64 + (k - 256)];
  wb[n] = (_Float16)v;
}

__device__ __forceinline__ float sigm(float v) {
  return __builtin_amdgcn_rcpf(1.0f + __expf(-v));
}
__device__ __forceinline__ float tanh_f(float v) {
  return 1.0f - 2.0f * __builtin_amdgcn_rcpf(1.0f + __expf(2.0f * v));
}

#define MFMA16(a, b, c) __builtin_amdgcn_mfma_f32_16x16x32_f16(a, b, c, 0, 0, 0)
#define FDOT(W, X, A) __builtin_amdgcn_fdot2(__builtin_bit_cast(f16x2, W), \
                                             __builtin_bit_cast(f16x2, X), A, false)

// ---------------- batched MFMA recurrence: 1 block = 16 sequences ----------------
// R13: R10-R12 were all bound by re-streaming r/z B-frags (demand ~290 regs >
// 256-reg budget at 2 waves/SIMD -> allocator degrades to reload-per-use;
// VGPR_Count 64/128/128 proved residency never happened; dur matched the
// 320-480 KB/step L2-restream model each round).
// Fix: grow the budget. 4 waves (256 thr), 1 wave/SIMD -> 512-VGPR unified file.
//  - each wave owns 4 col-tiles; r+z = 80 frags = 320 VGPR pinned, total demand
//    ~480 <= 512 -> true residency is finally feasible.
//  - A-frag LDS reads halve again (each a feeds 12 MFMAs): 40 b128/step.
//  - n-gate frags from LDS (128 KB), i_n frags streamed from L2 (32 KB/step,
//    also the allocator's pressure-relief valve: remat-able loads).
// Per-step/CU: LDS ~2700 cyc (A 480 + WN 1536 + writes/dumps ~650) = binding;
// MFMA 582/SIMD, VALU epilogue, VMEM all overlap. Predict ~620-700 us.
__global__ __launch_bounds__(THR, 1) void gru_kernel(
    const float* __restrict__ x,      // [B, T, I]
    const float* __restrict__ b_ih,   // [768]
    const float* __restrict__ b_hh,   // [768]
    const _Float16* __restrict__ wb,  // packed B fragments
    _Float16* __restrict__ HD,        // [NT][NB][NH] f16 hidden-state dump
    float* __restrict__ out)          // unused here (kept for symmetry)
{
  __shared__ __align__(16) _Float16 H[2][NSEQ][HS];   // 22016 B, double-buffered
  __shared__ __align__(16) _Float16 WN[8 * 16 * 512]; // 131072 B: n-gate frags (16 tiles)

  const int tid  = threadIdx.x;     // 0..255
  const int lane = tid & 63;
  const int w    = tid >> 6;        // wave 0..3
  const int q    = lane >> 4;       // quad 0..3
  const int col  = lane & 15;
  const int b0   = blockIdx.x * NSEQ;
  const int j0   = (4 * w + 0) * 16 + col;   // hidden units owned in epilogue
  const int j1   = (4 * w + 1) * 16 + col;
  const int j2   = (4 * w + 2) * 16 + col;
  const int j3   = (4 * w + 3) * 16 + col;

  const _Float16* wbL = wb + (size_t)lane * 8;

  // ---- stage n-gate frags to LDS (128 KB, coalesced float4) ----
  {
    const float4* src = (const float4*)(wb + (size_t)320 * 512);
    float4* dst = (float4*)WN;
    #pragma unroll
    for (int it = 0; it < 32; ++it) dst[tid + it * THR] = src[tid + it * THR];
  }
  // wave's n-frag base: frags [32w, 32w+32) of WN, i.e. tiles 4w..4w+3, kb 0..7
  const _Float16* wnW = WN + (size_t)(32 * w) * 512 + (size_t)lane * 8;

  // ---- persistent B fragments: r + z for 4 tiles (80 x half8 = 320 VGPR) ----
#define LR(T, k) half8 R##T##_##k = *(const half8*)(wbL + (size_t)((4 * w + T) * 10 + (k)) * 512);
  LR(0,0) LR(0,1) LR(0,2) LR(0,3) LR(0,4) LR(0,5) LR(0,6) LR(0,7) LR(0,8) LR(0,9)
  LR(1,0) LR(1,1) LR(1,2) LR(1,3) LR(1,4) LR(1,5) LR(1,6) LR(1,7) LR(1,8) LR(1,9)
  LR(2,0) LR(2,1) LR(2,2) LR(2,3) LR(2,4) LR(2,5) LR(2,6) LR(2,7) LR(2,8) LR(2,9)
  LR(3,0) LR(3,1) LR(3,2) LR(3,3) LR(3,4) LR(3,5) LR(3,6) LR(3,7) LR(3,8) LR(3,9)
#undef LR
#define LZ(T, k) half8 Z##T##_##k = *(const half8*)(wbL + (size_t)(160 + (4 * w + T) * 10 + (k)) * 512);
  LZ(0,0) LZ(0,1) LZ(0,2) LZ(0,3) LZ(0,4) LZ(0,5) LZ(0,6) LZ(0,7) LZ(0,8) LZ(0,9)
  LZ(1,0) LZ(1,1) LZ(1,2) LZ(1,3) LZ(1,4) LZ(1,5) LZ(1,6) LZ(1,7) LZ(1,8) LZ(1,9)
  LZ(2,0) LZ(2,1) LZ(2,2) LZ(2,3) LZ(2,4) LZ(2,5) LZ(2,6) LZ(2,7) LZ(2,8) LZ(2,9)
  LZ(3,0) LZ(3,1) LZ(3,2) LZ(3,3) LZ(3,4) LZ(3,5) LZ(3,6) LZ(3,7) LZ(3,8) LZ(3,9)
#undef LZ
  // Pin: asm result is opaque (non-rematerializable) -> allocator must keep live.
  asm("" : "+v"(R0_0), "+v"(R0_1), "+v"(R0_2), "+v"(R0_3), "+v"(R0_4),
           "+v"(R0_5), "+v"(R0_6), "+v"(R0_7), "+v"(R0_8), "+v"(R0_9));
  asm("" : "+v"(R1_0), "+v"(R1_1), "+v"(R1_2), "+v"(R1_3), "+v"(R1_4),
           "+v"(R1_5), "+v"(R1_6), "+v"(R1_7), "+v"(R1_8), "+v"(R1_9));
  asm("" : "+v"(R2_0), "+v"(R2_1), "+v"(R2_2), "+v"(R2_3), "+v"(R2_4),
           "+v"(R2_5), "+v"(R2_6), "+v"(R2_7), "+v"(R2_8), "+v"(R2_9));
  asm("" : "+v"(R3_0), "+v"(R3_1), "+v"(R3_2), "+v"(R3_3), "+v"(R3_4),
           "+v"(R3_5), "+v"(R3_6), "+v"(R3_7), "+v"(R3_8), "+v"(R3_9));
  asm("" : "+v"(Z0_0), "+v"(Z0_1), "+v"(Z0_2), "+v"(Z0_3), "+v"(Z0_4),
           "+v"(Z0_5), "+v"(Z0_6), "+v"(Z0_7), "+v"(Z0_8), "+v"(Z0_9));
  asm("" : "+v"(Z1_0), "+v"(Z1_1), "+v"(Z1_2), "+v"(Z1_3), "+v"(Z1_4),
           "+v"(Z1_5), "+v"(Z1_6), "+v"(Z1_7), "+v"(Z1_8), "+v"(Z1_9));
  asm("" : "+v"(Z2_0), "+v"(Z2_1), "+v"(Z2_2), "+v"(Z2_3), "+v"(Z2_4),
           "+v"(Z2_5), "+v"(Z2_6), "+v"(Z2_7), "+v"(Z2_8), "+v"(Z2_9));
  asm("" : "+v"(Z3_0), "+v"(Z3_1), "+v"(Z3_2), "+v"(Z3_3), "+v"(Z3_4),
           "+v"(Z3_5), "+v"(Z3_6), "+v"(Z3_7), "+v"(Z3_8), "+v"(Z3_9));

  // ---- i_n stream pointers (2 frags/tile, L2 re-read each step; loop-variant) ----
  uintptr_t pI0 = (uintptr_t)(wbL + (size_t)(448 + (4 * w + 0) * 2) * 512);
  uintptr_t pI1 = (uintptr_t)(wbL + (size_t)(448 + (4 * w + 1) * 2) * 512);
  uintptr_t pI2 = (uintptr_t)(wbL + (size_t)(448 + (4 * w + 2) * 2) * 512);
  uintptr_t pI3 = (uintptr_t)(wbL + (size_t)(448 + (4 * w + 3) * 2) * 512);

  const float br0  = b_ih[j0] + b_hh[j0];
  const float bz0  = b_ih[256 + j0] + b_hh[256 + j0];
  const float bin0 = b_ih[512 + j0];
  const float bhn0 = b_hh[512 + j0];
  const float br1  = b_ih[j1] + b_hh[j1];
  const float bz1  = b_ih[256 + j1] + b_hh[256 + j1];
  const float bin1 = b_ih[512 + j1];
  const float bhn1 = b_hh[512 + j1];
  const float br2  = b_ih[j2] + b_hh[j2];
  const float bz2  = b_ih[256 + j2] + b_hh[256 + j2];
  const float bin2 = b_ih[512 + j2];
  const float bhn2 = b_hh[512 + j2];
  const float br3  = b_ih[j3] + b_hh[j3];
  const float bz3  = b_ih[256 + j3] + b_hh[256 + j3];
  const float bin3 = b_ih[512 + j3];
  const float bhn3 = b_hh[512 + j3];

  // ---- init: zero H (both buffers), then x(t=0) into H[0] ----
  {
    float4* hz = (float4*)H;
    #pragma unroll
    for (int it = 0; it < 6; ++it) {
      int idx = tid + it * THR;
      if (idx < (int)(sizeof(H) / 16)) hz[idx] = float4{0, 0, 0, 0};
    }
  }
  __syncthreads();
  // rows w, w+4, w+8, w+12 staged by wave w
  H[0][w +  0][256 + lane] = (_Float16)x[(size_t)(b0 + w +  0) * (NT * NI) + lane];
  H[0][w +  4][256 + lane] = (_Float16)x[(size_t)(b0 + w +  4) * (NT * NI) + lane];
  H[0][w +  8][256 + lane] = (_Float16)x[(size_t)(b0 + w +  8) * (NT * NI) + lane];
  H[0][w + 12][256 + lane] = (_Float16)x[(size_t)(b0 + w + 12) * (NT * NI) + lane];
  float h0_0 = 0.0f, h0_1 = 0.0f, h0_2 = 0.0f, h0_3 = 0.0f;
  float h1_0 = 0.0f, h1_1 = 0.0f, h1_2 = 0.0f, h1_3 = 0.0f;
  float h2_0 = 0.0f, h2_1 = 0.0f, h2_2 = 0.0f, h2_3 = 0.0f;
  float h3_0 = 0.0f, h3_1 = 0.0f, h3_2 = 0.0f, h3_3 = 0.0f;
  const float* xp0 = x + (size_t)(b0 + w +  0) * (NT * NI) + 64 + lane;
  const float* xp1 = x + (size_t)(b0 + w +  4) * (NT * NI) + 64 + lane;
  const float* xp2 = x + (size_t)(b0 + w +  8) * (NT * NI) + 64 + lane;
  const float* xp3 = x + (size_t)(b0 + w + 12) * (NT * NI) + 64 + lane;
  __syncthreads();

  for (int t = 0; t < NT; ++t) {
    const int cur = t & 1, nxt = cur ^ 1;
    // keep i-stream loads loop-variant (no LICM hoist)
    asm("" : "+v"(pI0), "+v"(pI1), "+v"(pI2), "+v"(pI3));
    const half8* sI0 = (const half8*)pI0;
    const half8* sI1 = (const half8*)pI1;
    const half8* sI2 = (const half8*)pI2;
    const half8* sI3 = (const half8*)pI3;

    float xv0 = 0.0f, xv1 = 0.0f, xv2 = 0.0f, xv3 = 0.0f;
    if (t + 1 < NT) {
      xv0 = xp0[(size_t)t * 64]; xv1 = xp1[(size_t)t * 64];
      xv2 = xp2[(size_t)t * 64]; xv3 = xp3[(size_t)t * 64];
    }

    // ---- dump h_{t-1} (h-part of H[cur]) to HD[t-1]: 256 thr x 2 units ----
    if (t > 0) {
      int row = tid >> 5, ch = tid & 31;
      float4 hv0 = *(const float4*)&H[cur][row][ch * 8];
      *(float4*)(HD + ((size_t)(t - 1) * NB + b0 + row) * NH + ch * 8) = hv0;
      float4 hv1 = *(const float4*)&H[cur][row + 8][ch * 8];
      *(float4*)(HD + ((size_t)(t - 1) * NB + b0 + row + 8) * NH + ch * 8) = hv1;
    }

    // ---- GEMM: A row = seq = col, 120 MFMAs/wave (4 tiles x 3 gates x 10 kb) ----
    const _Float16* hrow = &H[cur][col][q * 8];
    floatx4 cR0 = {0,0,0,0}, cZ0 = {0,0,0,0}, cN0 = {0,0,0,0}, cI0 = {0,0,0,0};
    floatx4 cR1 = {0,0,0,0}, cZ1 = {0,0,0,0}, cN1 = {0,0,0,0}, cI1 = {0,0,0,0};
    floatx4 cR2 = {0,0,0,0}, cZ2 = {0,0,0,0}, cN2 = {0,0,0,0}, cI2 = {0,0,0,0};
    floatx4 cR3 = {0,0,0,0}, cZ3 = {0,0,0,0}, cN3 = {0,0,0,0}, cI3 = {0,0,0,0};
#define KGRP(k) { \
    half8 a  = *(const half8*)(hrow + (k) * 32); \
    half8 n0 = *(const half8*)(wnW + (size_t)(0 * 8 + (k)) * 512); \
    half8 n1 = *(const half8*)(wnW + (size_t)(1 * 8 + (k)) * 512); \
    half8 n2 = *(const half8*)(wnW + (size_t)(2 * 8 + (k)) * 512); \
    half8 n3 = *(const half8*)(wnW + (size_t)(3 * 8 + (k)) * 512); \
    cR0 = MFMA16(a, R0_##k, cR0); cR1 = MFMA16(a, R1_##k, cR1); \
    cR2 = MFMA16(a, R2_##k, cR2); cR3 = MFMA16(a, R3_##k, cR3); \
    cZ0 = MFMA16(a, Z0_##k, cZ0); cZ1 = MFMA16(a, Z1_##k, cZ1); \
    cZ2 = MFMA16(a, Z2_##k, cZ2); cZ3 = MFMA16(a, Z3_##k, cZ3); \
    cN0 = MFMA16(a, n0, cN0); cN1 = MFMA16(a, n1, cN1); \
    cN2 = MFMA16(a, n2, cN2); cN3 = MFMA16(a, n3, cN3); }
    KGRP(0) KGRP(1) KGRP(2) KGRP(3) KGRP(4)
    half8 ia0 = sI0[0], ia1 = sI1[0], ia2 = sI2[0], ia3 = sI3[0];  // frag kb=8
    KGRP(5)
    half8 ib0 = sI0[64], ib1 = sI1[64], ib2 = sI2[64], ib3 = sI3[64]; // frag kb=9
    KGRP(6) KGRP(7)
#undef KGRP
    { half8 a = *(const half8*)(hrow + 8 * 32);
      cR0 = MFMA16(a, R0_8, cR0); cR1 = MFMA16(a, R1_8, cR1);
      cR2 = MFMA16(a, R2_8, cR2); cR3 = MFMA16(a, R3_8, cR3);
      cZ0 = MFMA16(a, Z0_8, cZ0); cZ1 = MFMA16(a, Z1_8, cZ1);
      cZ2 = MFMA16(a, Z2_8, cZ2); cZ3 = MFMA16(a, Z3_8, cZ3);
      cI0 = MFMA16(a, ia0, cI0);  cI1 = MFMA16(a, ia1, cI1);
      cI2 = MFMA16(a, ia2, cI2);  cI3 = MFMA16(a, ia3, cI3); }
    { half8 a = *(const half8*)(hrow + 9 * 32);
      cR0 = MFMA16(a, R0_9, cR0); cR1 = MFMA16(a, R1_9, cR1);
      cR2 = MFMA16(a, R2_9, cR2); cR3 = MFMA16(a, R3_9, cR3);
      cZ0 = MFMA16(a, Z0_9, cZ0); cZ1 = MFMA16(a, Z1_9, cZ1);
      cZ2 = MFMA16(a, Z2_9, cZ2); cZ3 = MFMA16(a, Z3_9, cZ3);
      cI0 = MFMA16(a, ib0, cI0);  cI1 = MFMA16(a, ib1, cI1);
      cI2 = MFMA16(a, ib2, cI2);  cI3 = MFMA16(a, ib3, cI3); }

    // ---- in-register epilogue: lane owns (j0..j3) x (seqs q*4..q*4+3) ----
#define GATE(m, hvar, CR, CZ, CN, CI, BR_, BZ_, BI_, BH_, J) { \
    float rr = sigm(CR[m] + BR_); \
    float zz = sigm(CZ[m] + BZ_); \
    float nn = tanh_f(CI[m] + BI_ + rr * (CN[m] + BH_)); \
    hvar = (1.0f - zz) * nn + zz * hvar; \
    H[nxt][q * 4 + (m)][J] = (_Float16)hvar; }
    GATE(0, h0_0, cR0, cZ0, cN0, cI0, br0, bz0, bin0, bhn0, j0)
    GATE(1, h0_1, cR0, cZ0, cN0, cI0, br0, bz0, bin0, bhn0, j0)
    GATE(2, h0_2, cR0, cZ0, cN0, cI0, br0, bz0, bin0, bhn0, j0)
    GATE(3, h0_3, cR0, cZ0, cN0, cI0, br0, bz0, bin0, bhn0, j0)
    GATE(0, h1_0, cR1, cZ1, cN1, cI1, br1, bz1, bin1, bhn1, j1)
    GATE(1, h1_1, cR1, cZ1, cN1, cI1, br1, bz1, bin1, bhn1, j1)
    GATE(2, h1_2, cR1, cZ1, cN1, cI1, br1, bz1, bin1, bhn1, j1)
    GATE(3, h1_3, cR1, cZ1, cN1, cI1, br1, bz1, bin1, bhn1, j1)
    GATE(0, h2_0, cR2, cZ2, cN2, cI2, br2, bz2, bin2, bhn2, j2)
    GATE(1, h2_1, cR2, cZ2, cN2, cI2, br2, bz2, bin2, bhn2, j2)
    GATE(2, h2_2, cR2, cZ2, cN2, cI2, br2, bz2, bin2, bhn2, j2)
    GATE(3, h2_3, cR2, cZ2, cN2, cI2, br2, bz2, bin2, bhn2, j2)
    GATE(0, h3_0, cR3, cZ3, cN3, cI3, br3, bz3, bin3, bhn3, j3)
    GATE(1, h3_1, cR3, cZ3, cN3, cI3, br3, bz3, bin3, bhn3, j3)
    GATE(2, h3_2, cR3, cZ3, cN3, cI3, br3, bz3, bin3, bhn3, j3)
    GATE(3, h3_3, cR3, cZ3, cN3, cI3, br3, bz3, bin3, bhn3, j3)
#undef GATE
    if (t + 1 < NT) {
      H[nxt][w +  0][256 + lane] = (_Float16)xv0;
      H[nxt][w +  4][256 + lane] = (_Float16)xv1;
      H[nxt][w +  8][256 + lane] = (_Float16)xv2;
      H[nxt][w + 12][256 + lane] = (_Float16)xv3;
    }

    __syncthreads();   // the single per-step barrier
  }

  // ---- final dump: h_{NT-1} lives in H[0] (NT even) ----
  {
    int row = tid >> 5, ch = tid & 31;
    float4 hv0 = *(const float4*)&H[0][row][ch * 8];
    *(float4*)(HD + ((size_t)(NT - 1) * NB + b0 + row) * NH + ch * 8) = hv0;
    float4 hv1 = *(const float4*)&H[0][row + 8][ch * 8];
    *(float4*)(HD + ((size_t)(NT - 1) * NB + b0 + row + 8) * NH + ch * 8) = hv1;
  }
}

// ---------------- epilogue: out[t][b] = HD[t][b][:] . w_out + b_out ----------------
__global__ __launch_bounds__(256) void gru_out_kernel(
    const _Float16* __restrict__ HD, const float* __restrict__ w_out,
    const float* __restrict__ b_out, float* __restrict__ out)
{
  __shared__ __align__(16) _Float16 WL[NH];
  int tid = threadIdx.x;
  WL[tid] = (_Float16)w_out[tid];
  __syncthreads();
  int gid = blockIdx.x * 256 + tid;          // gid = t*NB + b
  const float4* hp = (const float4*)(HD + (size_t)gid * NH);
  const float4* wp = (const float4*)WL;
  float acc = 0.0f;
  #pragma unroll
  for (int i = 0; i < NH / 8; ++i) {
    float4 hv = hp[i];
    float4 wv = wp[i];
    acc = FDOT(hv.x, wv.x, acc);
    acc = FDOT(hv.y, wv.y, acc);
    acc = FDOT(hv.z, wv.z, acc);
    acc = FDOT(hv.w, wv.w, acc);
  }
  out[gid] = acc + b_out[0];
}

extern "C" void kernel_launch(void* const* d_in, const int* in_sizes, int n_in,
                              void* d_out, int out_size, void* d_ws, size_t ws_size,
                              hipStream_t stream) {
  const float* x     = (const float*)d_in[0];
  const float* w_ih  = (const float*)d_in[1];
  const float* w_hh  = (const float*)d_in[2];
  const float* b_ih  = (const float*)d_in[3];
  const float* b_hh  = (const float*)d_in[4];
  const float* w_out = (const float*)d_in[5];
  const float* b_out = (const float*)d_in[6];
  float* out = (float*)d_out;

  _Float16* wb = (_Float16*)d_ws;            // 480 KB packed B fragments
  _Float16* HD = wb + WB_N;                  // 64 MB hidden-state dump (16B-aligned)

  gru_prep_kernel<<<(WB_N + 255) / 256, 256, 0, stream>>>(w_ih, w_hh, wb);
  gru_kernel<<<NBLK, THR, 0, stream>>>(x, b_ih, b_hh, wb, HD, out);
  gru_out_kernel<<<(NT * NB) / 256, 256, 0, stream>>>(HD, w_out, b_out, out);
}

// Round 5
// 1500.583 us; speedup vs baseline: 1.3332x; 1.3332x over previous
//
#include <hip/hip_runtime.h>

typedef _Float16 half8 __attribute__((ext_vector_type(8)));
typedef _Float16 f16x2 __attribute__((ext_vector_type(2)));
typedef float floatx4 __attribute__((ext_vector_type(4)));

#define NB 256    // batch
#define NT 512    // time
#define NI 64     // input
#define NH 256    // hidden
#define NSEQ 16   // sequences per block
#define NBLK (NB / NSEQ)   // 16 blocks
#define THR 512            // 8 waves, 2 waves/SIMD -> 256-reg cap (the HARD addressable max)
#define HS 344             // H row stride in f16

// B-fragment pack (VALIDATED R9/R10): 480 frags x 64 lanes x 8 f16.
// Cols: [0,256)=r, [256,512)=z, [512,768)=h_n, [768,1024)=i_n. K: [0,256)=h, [256,320)=x.
// frag f: r: tt*10+kb; z: 160+tt*10+kb; h_n: 320+tt*8+kb (kb<8); i_n: 448+tt*2+(kb-8).
// wb[f*512 + lane*8 + i] = W[k = kb*32 + (lane>>4)*8 + i][n = tt*16 + (lane&15)]
#define WB_N (480 * 512)

__global__ __launch_bounds__(256) void gru_prep_kernel(
    const float* __restrict__ w_ih, const float* __restrict__ w_hh,
    _Float16* __restrict__ wb)
{
  int n = blockIdx.x * 256 + threadIdx.x;
  if (n >= WB_N) return;
  int i = n & 7, l = (n >> 3) & 63, f = n >> 9;
  int q = l >> 4, col = l & 15;
  int tt, kb, gate;
  if (f < 160)      { tt = f / 10;               kb = f % 10;        gate = 0; }
  else if (f < 320) { int f2 = f - 160; tt = f2 / 10; kb = f2 % 10;  gate = 1; }
  else if (f < 448) { int f3 = f - 320; tt = f3 / 8;  kb = f3 % 8;   gate = 2; }
  else              { int f4 = f - 448; tt = f4 / 2;  kb = 8 + (f4 & 1); gate = 3; }
  int j = (tt & 15) * 16 + col;
  int k = kb * 32 + q * 8 + i;
  float v;
  if (gate == 0)      v = (k < 256) ? w_hh[(0   + j) * 256 + k] : w_ih[(0   + j) * 64 + (k - 256)];
  else if (gate == 1) v = (k < 256) ? w_hh[(256 + j) * 256 + k] : w_ih[(256 + j) * 64 + (k - 256)];
  else if (gate == 2) v = w_hh[(512 + j) * 256 + k];
  else                v = w_ih[(512 + j) * 64 + (k - 256)];
  wb[n] = (_Float16)v;
}

__device__ __forceinline__ float sigm(float v) {
  return __builtin_amdgcn_rcpf(1.0f + __expf(-v));
}
__device__ __forceinline__ float tanh_f(float v) {
  return 1.0f - 2.0f * __builtin_amdgcn_rcpf(1.0f + __expf(2.0f * v));
}

#define MFMA16(a, b, c) __builtin_amdgcn_mfma_f32_16x16x32_f16(a, b, c, 0, 0, 0)
#define FDOT(W, X, A) __builtin_amdgcn_fdot2(__builtin_bit_cast(f16x2, W), \
                                             __builtin_bit_cast(f16x2, X), A, false)

// ---------------- batched MFMA recurrence: 1 block = 16 sequences ----------------
// R15: three-tier B-operand, sized to the REAL 256-addressable-VGPR wall:
//  - pinned (asm, 128 v): r_h + z_h, 8 kb-frags x 2 tiles x 2 gates = 32 frags.
//    (R12 pinned 40 = 160 v and the allocator collapsed to reload-per-use;
//     R13 proved >256 "v" is architecturally impossible.)
//  - LDS (96 KB): n_h for each wave's EVEN tile (64 frags) + all i_n (32 frags).
//  - L2 stream per step (VMEM pipe, ~132 KB): n_h odd tile (8/wave, 3-deep
//    prefetch) + r_x/z_x kb=8,9 (8/wave, issued in groups 5-6 for k=8,9).
// Per-step/CU: LDS ~2780 cyc (binding), VMEM ~2100, MFMA ~580/SIMD, epilogue
// VALU — all overlapped. Workspace = R12's known-good 64.5 MB. Est demand ~235 v.
__global__ __launch_bounds__(THR, 2) void gru_kernel(
    const float* __restrict__ x,      // [B, T, I]
    const float* __restrict__ b_ih,   // [768]
    const float* __restrict__ b_hh,   // [768]
    const _Float16* __restrict__ wb,  // packed B fragments
    _Float16* __restrict__ HD,        // [NT][NB][NH] f16 hidden-state dump
    float* __restrict__ out)          // unused here (kept for symmetry)
{
  __shared__ __align__(16) _Float16 H[2][NSEQ][HS];   // 22016 B, double-buffered
  __shared__ __align__(16) _Float16 WN[96 * 512];     // 98304 B: n_h even tiles + i_n

  const int tid  = threadIdx.x;
  const int lane = tid & 63;
  const int w    = tid >> 6;        // wave 0..7
  const int q    = lane >> 4;       // quad 0..3
  const int col  = lane & 15;
  const int b0   = blockIdx.x * NSEQ;
  const int j0   = (2 * w) * 16 + col;      // tile t0 = 2w
  const int j1   = j0 + 16;                 // tile t1 = 2w+1

  const _Float16* wbL = wb + (size_t)lane * 8;

  // ---- stage to LDS: slots [0,64) = n_h frags 320+16w+k (even tiles);
  //      slots [64,96) = i_n frags 448+s. 6144 float4, coalesced-ish. ----
  {
    const float4* src = (const float4*)wb;
    float4* dst = (float4*)WN;
    #pragma unroll
    for (int it = 0; it < 12; ++it) {
      int d = tid + it * THR;             // 0..6143
      int slot = d >> 6, elem = d & 63;   // slot wave-uniform (64 thr/slot)
      int f = (slot < 64) ? (320 + ((slot >> 3) << 4) + (slot & 7))
                          : (448 + (slot - 64));
      dst[d] = src[(size_t)f * 64 + elem];
    }
  }
  const _Float16* wnB = WN + (size_t)lane * 8;

  // ---- persistent B fragments: r_h + z_h both tiles (32 x half8 = 128 VGPR) ----
#define LR(T, k) half8 R##T##_##k = *(const half8*)(wbL + (size_t)((2 * w + T) * 10 + (k)) * 512);
  LR(0,0) LR(0,1) LR(0,2) LR(0,3) LR(0,4) LR(0,5) LR(0,6) LR(0,7)
  LR(1,0) LR(1,1) LR(1,2) LR(1,3) LR(1,4) LR(1,5) LR(1,6) LR(1,7)
#undef LR
#define LZ(T, k) half8 Z##T##_##k = *(const half8*)(wbL + (size_t)(160 + (2 * w + T) * 10 + (k)) * 512);
  LZ(0,0) LZ(0,1) LZ(0,2) LZ(0,3) LZ(0,4) LZ(0,5) LZ(0,6) LZ(0,7)
  LZ(1,0) LZ(1,1) LZ(1,2) LZ(1,3) LZ(1,4) LZ(1,5) LZ(1,6) LZ(1,7)
#undef LZ
  // Pin: opaque asm result is non-rematerializable -> must stay resident.
  asm("" : "+v"(R0_0), "+v"(R0_1), "+v"(R0_2), "+v"(R0_3),
           "+v"(R0_4), "+v"(R0_5), "+v"(R0_6), "+v"(R0_7));
  asm("" : "+v"(R1_0), "+v"(R1_1), "+v"(R1_2), "+v"(R1_3),
           "+v"(R1_4), "+v"(R1_5), "+v"(R1_6), "+v"(R1_7));
  asm("" : "+v"(Z0_0), "+v"(Z0_1), "+v"(Z0_2), "+v"(Z0_3),
           "+v"(Z0_4), "+v"(Z0_5), "+v"(Z0_6), "+v"(Z0_7));
  asm("" : "+v"(Z1_0), "+v"(Z1_1), "+v"(Z1_2), "+v"(Z1_3),
           "+v"(Z1_4), "+v"(Z1_5), "+v"(Z1_6), "+v"(Z1_7));

  // ---- stream base pointers (loop-variant via asm; re-read from L2 each step) ----
  uintptr_t pN1  = (uintptr_t)(wbL + (size_t)(320 + 16 * w + 8) * 512);        // n_h tile1
  uintptr_t pRX0 = (uintptr_t)(wbL + (size_t)((2 * w) * 10 + 8) * 512);        // r_x tile0
  uintptr_t pRX1 = (uintptr_t)(wbL + (size_t)((2 * w + 1) * 10 + 8) * 512);    // r_x tile1
  uintptr_t pZX0 = (uintptr_t)(wbL + (size_t)(160 + (2 * w) * 10 + 8) * 512);  // z_x tile0
  uintptr_t pZX1 = (uintptr_t)(wbL + (size_t)(160 + (2 * w + 1) * 10 + 8) * 512);

  const float br0  = b_ih[j0] + b_hh[j0];
  const float bz0  = b_ih[256 + j0] + b_hh[256 + j0];
  const float bin0 = b_ih[512 + j0];
  const float bhn0 = b_hh[512 + j0];
  const float br1  = b_ih[j1] + b_hh[j1];
  const float bz1  = b_ih[256 + j1] + b_hh[256 + j1];
  const float bin1 = b_ih[512 + j1];
  const float bhn1 = b_hh[512 + j1];

  // ---- init: zero H (both buffers), then x(t=0) into H[0] ----
  {
    float4* hz = (float4*)H;
    #pragma unroll
    for (int it = 0; it < 3; ++it) {
      int idx = tid + it * THR;
      if (idx < (int)(sizeof(H) / 16)) hz[idx] = float4{0, 0, 0, 0};
    }
  }
  __syncthreads();
  H[0][w][256 + lane]     = (_Float16)x[(size_t)(b0 + w)     * (NT * NI) + lane];
  H[0][w + 8][256 + lane] = (_Float16)x[(size_t)(b0 + w + 8) * (NT * NI) + lane];
  float h00 = 0.0f, h01 = 0.0f, h02 = 0.0f, h03 = 0.0f;
  float h10 = 0.0f, h11 = 0.0f, h12 = 0.0f, h13 = 0.0f;
  const float* xp0 = x + (size_t)(b0 + w)     * (NT * NI) + 64 + lane;
  const float* xp1 = x + (size_t)(b0 + w + 8) * (NT * NI) + 64 + lane;
  __syncthreads();

  for (int t = 0; t < NT; ++t) {
    const int cur = t & 1, nxt = cur ^ 1;
    // keep stream loads loop-variant (no LICM hoist -> no extra persistent regs)
    asm("" : "+v"(pN1), "+v"(pRX0), "+v"(pRX1), "+v"(pZX0), "+v"(pZX1));
    const half8* sN1  = (const half8*)pN1;    // frag stride = 512 f16 = 64 half8
    const half8* sRX0 = (const half8*)pRX0;
    const half8* sRX1 = (const half8*)pRX1;
    const half8* sZX0 = (const half8*)pZX0;
    const half8* sZX1 = (const half8*)pZX1;

    // prefetch first 3 n1 frags (consumed in groups 0..2)
    half8 n1_0 = sN1[0 * 64], n1_1 = sN1[1 * 64], n1_2 = sN1[2 * 64];

    float xv0 = 0.0f, xv1 = 0.0f;
    if (t + 1 < NT) { xv0 = xp0[(size_t)t * 64]; xv1 = xp1[(size_t)t * 64]; }

    // ---- dump h_{t-1} (h-part of H[cur]) to HD[t-1]: all 512 threads ----
    if (t > 0) {
      int row = tid >> 5, ch = tid & 31;
      float4 hv = *(const float4*)&H[cur][row][ch * 8];
      *(float4*)(HD + ((size_t)(t - 1) * NB + b0 + row) * NH + ch * 8) = hv;
    }

    // ---- GEMM: A row = seq = col (validated), 60 MFMAs/wave ----
    const _Float16* hrow = &H[cur][col][q * 8];
    floatx4 cR0 = {0,0,0,0}, cZ0 = {0,0,0,0}, cN0 = {0,0,0,0}, cI0 = {0,0,0,0};
    floatx4 cR1 = {0,0,0,0}, cZ1 = {0,0,0,0}, cN1 = {0,0,0,0}, cI1 = {0,0,0,0};
#define KGRP(k, N1R) { \
    half8 a  = *(const half8*)(hrow + (k) * 32); \
    half8 n0 = *(const half8*)(wnB + (size_t)(w * 8 + (k)) * 512); \
    cR0 = MFMA16(a, R0_##k, cR0); cR1 = MFMA16(a, R1_##k, cR1); \
    cZ0 = MFMA16(a, Z0_##k, cZ0); cZ1 = MFMA16(a, Z1_##k, cZ1); \
    cN0 = MFMA16(a, n0, cN0);     cN1 = MFMA16(a, N1R, cN1); }
    KGRP(0, n1_0)  half8 n1_3 = sN1[3 * 64];
    KGRP(1, n1_1)  half8 n1_4 = sN1[4 * 64];
    KGRP(2, n1_2)  half8 n1_5 = sN1[5 * 64];
    KGRP(3, n1_3)  half8 n1_6 = sN1[6 * 64];
    KGRP(4, n1_4)  half8 n1_7 = sN1[7 * 64];
    KGRP(5, n1_5)  half8 rxA0 = sRX0[0], rxA1 = sRX1[0];
                   half8 zxA0 = sZX0[0], zxA1 = sZX1[0];
    KGRP(6, n1_6)  half8 rxB0 = sRX0[64], rxB1 = sRX1[64];
                   half8 zxB0 = sZX0[64], zxB1 = sZX1[64];
                   half8 iA0 = *(const half8*)(wnB + (size_t)(64 + 4 * w + 0) * 512);
                   half8 iA1 = *(const half8*)(wnB + (size_t)(64 + 4 * w + 2) * 512);
    KGRP(7, n1_7)  half8 iB0 = *(const half8*)(wnB + (size_t)(64 + 4 * w + 1) * 512);
                   half8 iB1 = *(const half8*)(wnB + (size_t)(64 + 4 * w + 3) * 512);
#undef KGRP
    // k=8: x cols [0,32) — streamed r_x/z_x kb=8, LDS i_n kb=8
    { half8 a = *(const half8*)(hrow + 8 * 32);
      cR0 = MFMA16(a, rxA0, cR0); cR1 = MFMA16(a, rxA1, cR1);
      cZ0 = MFMA16(a, zxA0, cZ0); cZ1 = MFMA16(a, zxA1, cZ1);
      cI0 = MFMA16(a, iA0, cI0);  cI1 = MFMA16(a, iA1, cI1); }
    // k=9: x cols [32,64)
    { half8 a = *(const half8*)(hrow + 9 * 32);
      cR0 = MFMA16(a, rxB0, cR0); cR1 = MFMA16(a, rxB1, cR1);
      cZ0 = MFMA16(a, zxB0, cZ0); cZ1 = MFMA16(a, zxB1, cZ1);
      cI0 = MFMA16(a, iB0, cI0);  cI1 = MFMA16(a, iB1, cI1); }

    // ---- in-register epilogue: lane owns (j0,j1) x (seqs q*4..q*4+3) ----
#define GATE(m, hvar, CR, CZ, CN, CI, BR_, BZ_, BI_, BH_, J) { \
    float rr = sigm(CR[m] + BR_); \
    float zz = sigm(CZ[m] + BZ_); \
    float nn = tanh_f(CI[m] + BI_ + rr * (CN[m] + BH_)); \
    hvar = (1.0f - zz) * nn + zz * hvar; \
    H[nxt][q * 4 + (m)][J] = (_Float16)hvar; }
    GATE(0, h00, cR0, cZ0, cN0, cI0, br0, bz0, bin0, bhn0, j0)
    GATE(1, h01, cR0, cZ0, cN0, cI0, br0, bz0, bin0, bhn0, j0)
    GATE(2, h02, cR0, cZ0, cN0, cI0, br0, bz0, bin0, bhn0, j0)
    GATE(3, h03, cR0, cZ0, cN0, cI0, br0, bz0, bin0, bhn0, j0)
    GATE(0, h10, cR1, cZ1, cN1, cI1, br1, bz1, bin1, bhn1, j1)
    GATE(1, h11, cR1, cZ1, cN1, cI1, br1, bz1, bin1, bhn1, j1)
    GATE(2, h12, cR1, cZ1, cN1, cI1, br1, bz1, bin1, bhn1, j1)
    GATE(3, h13, cR1, cZ1, cN1, cI1, br1, bz1, bin1, bhn1, j1)
#undef GATE
    if (t + 1 < NT) {
      H[nxt][w][256 + lane]     = (_Float16)xv0;
      H[nxt][w + 8][256 + lane] = (_Float16)xv1;
    }

    __syncthreads();   // the single per-step barrier
  }

  // ---- final dump: h_{NT-1} lives in H[0] (NT even) ----
  {
    int row = tid >> 5, ch = tid & 31;
    float4 hv = *(const float4*)&H[0][row][ch * 8];
    *(float4*)(HD + ((size_t)(NT - 1) * NB + b0 + row) * NH + ch * 8) = hv;
  }
}

// ---------------- epilogue: out[t][b] = HD[t][b][:] . w_out + b_out ----------------
__global__ __launch_bounds__(256) void gru_out_kernel(
    const _Float16* __restrict__ HD, const float* __restrict__ w_out,
    const float* __restrict__ b_out, float* __restrict__ out)
{
  __shared__ __align__(16) _Float16 WL[NH];
  int tid = threadIdx.x;
  WL[tid] = (_Float16)w_out[tid];
  __syncthreads();
  int gid = blockIdx.x * 256 + tid;          // gid = t*NB + b
  const float4* hp = (const float4*)(HD + (size_t)gid * NH);
  const float4* wp = (const float4*)WL;
  float acc = 0.0f;
  #pragma unroll
  for (int i = 0; i < NH / 8; ++i) {
    float4 hv = hp[i];
    float4 wv = wp[i];
    acc = FDOT(hv.x, wv.x, acc);
    acc = FDOT(hv.y, wv.y, acc);
    acc = FDOT(hv.z, wv.z, acc);
    acc = FDOT(hv.w, wv.w, acc);
  }
  out[gid] = acc + b_out[0];
}

extern "C" void kernel_launch(void* const* d_in, const int* in_sizes, int n_in,
                              void* d_out, int out_size, void* d_ws, size_t ws_size,
                              hipStream_t stream) {
  const float* x     = (const float*)d_in[0];
  const float* w_ih  = (const float*)d_in[1];
  const float* w_hh  = (const float*)d_in[2];
  const float* b_ih  = (const float*)d_in[3];
  const float* b_hh  = (const float*)d_in[4];
  const float* w_out = (const float*)d_in[5];
  const float* b_out = (const float*)d_in[6];
  float* out = (float*)d_out;

  _Float16* wb = (_Float16*)d_ws;            // 480 KB packed B fragments
  _Float16* HD = wb + WB_N;                  // 64 MB hidden-state dump (16B-aligned)

  gru_prep_kernel<<<(WB_N + 255) / 256, 256, 0, stream>>>(w_ih, w_hh, wb);
  gru_kernel<<<NBLK, THR, 0, stream>>>(x, b_ih, b_hh, wb, HD, out);
  gru_out_kernel<<<(NT * NB) / 256, 256, 0, stream>>>(HD, w_out, b_out, out);
}